// Round 12
// baseline (208.449 us; speedup 1.0000x reference)
//
#include <hip/hip_runtime.h>
#include <hip/hip_bf16.h>

// Problem dims (hardcoded): B=4, S=2048, D=768, H=12, hd=64
//
// Accounting (R11, best=205.0us): attn(59.6) + gemm_qkv(~51) + gemm_o(~23)
// + prep(~10) + ~61us fixed. Settled: attn R0 structure, no setprio
// (R9: -4us, lockstep regime); gemm_qkv 128x128 2-buffer + V-transpose
// epilogue (R9: -15us); XCD remaps neutral-kept.
// This round: mirror the V-epilogue win onto Q/K — RoPE'd acc goes
// through a pitch-80 LDS tile, then coalesced row stores of qkv[s][64]
// (was: 64x 2-byte scattered stores/thread over 25MB, 2x the V bytes).
typedef __bf16 bf16;
typedef __bf16 bf16x8 __attribute__((ext_vector_type(8)));
typedef __bf16 bf16x4 __attribute__((ext_vector_type(4)));
typedef short  s16x4  __attribute__((ext_vector_type(4)));
typedef float  f32x4  __attribute__((ext_vector_type(4)));

#if defined(__has_builtin)
#if __has_builtin(__builtin_amdgcn_mfma_f32_16x16x16bf16_1k)
#define HAVE_MFMA16 1
#endif
#if __has_builtin(__builtin_amdgcn_exp2f)
#define EXP2(x) __builtin_amdgcn_exp2f(x)
#else
#define EXP2(x) exp2f(x)
#endif
#else
#define EXP2(x) exp2f(x)
#endif

__device__ __forceinline__ void gl_lds16(const void* g, void* l) {
  __builtin_amdgcn_global_load_lds(
      (__attribute__((address_space(1))) const void*)g,
      (__attribute__((address_space(3))) void*)l, 16, 0, 0);
}

__device__ __forceinline__ f32x4 mfma32(bf16x8 a, bf16x8 b, f32x4 c) {
  return __builtin_amdgcn_mfma_f32_16x16x32_bf16(a, b, c, 0, 0, 0);
}
#if HAVE_MFMA16
__device__ __forceinline__ f32x4 mfma16(s16x4 a, s16x4 b, f32x4 c) {
  return __builtin_amdgcn_mfma_f32_16x16x16bf16_1k(a, b, c, 0, 0, 0);
}
#endif

// ---------------- prep: fp32->bf16 convert (x, W_QKV, W_O) + RoPE trig table
// tab[b*2048+s][d2] = (cos, sin) of pos*theta^(-d2/32).
__global__ void prep(const float* __restrict__ a, bf16* __restrict__ da,
                     const float* __restrict__ b, bf16* __restrict__ db,
                     const float* __restrict__ c, bf16* __restrict__ dc,
                     const int* __restrict__ tpos, const int* __restrict__ thetap,
                     float2* __restrict__ tab) {
  int bx = blockIdx.x;
  if (bx >= 8448) {                       // trig table blocks
    int i = (bx - 8448) * 256 + threadIdx.x; // < 4*2048*32 = 262144
    int d2 = i & 31;
    int bs = i >> 5;                      // b*2048+s
    float lt = log2f((float)(*thetap));
    float fr = exp2f(-(float)d2 * (1.0f / 32.0f) * lt); // theta^(-d2/32)
    float ang = (float)tpos[bs] * fr;
    float sn, cs;
    sincosf(ang, &sn, &cs);
    tab[i] = make_float2(cs, sn);
    return;
  }
  const float* s; bf16* d; int i;
  if (bx < 6144)      { s = a; d = da; i = bx * 256 + threadIdx.x; }
  else if (bx < 7872) { s = b; d = db; i = (bx - 6144) * 256 + threadIdx.x; }
  else                { s = c; d = dc; i = (bx - 7872) * 256 + threadIdx.x; }
  float4 v = ((const float4*)s)[i];
  bf16x4 o;
  o[0] = (bf16)v.x; o[1] = (bf16)v.y; o[2] = (bf16)v.z; o[3] = (bf16)v.w;
  ((bf16x4*)d)[i] = o;
}

// ---------------- GEMM (QKV): C = A[M][K] * B[N][K]^T, K=768, 128x128 tile
// 2-buffer skeleton, grid (64,18) default dispatch, launch_bounds(256,4).
// Epilogues all go through LDS for coalesced stores:
//  mat==2 (V): transpose to Vout[b][h][64][2048] (R9: -15us).
//  mat<2 (Q/K): RoPE in fp32 regs (pair partner via __shfl_xor(v,1),
//  Q scaled by 1/sqrt(64)*log2(e)), then per-head pitch-80 LDS tile ->
//  coalesced qkv[s][64] row stores (was 64x 2B scattered stores/thread).
__global__ __launch_bounds__(256, 4)
void gemm_qkv(const bf16* __restrict__ A, const bf16* __restrict__ Bm,
              bf16* __restrict__ Cout, bf16* __restrict__ Vout,
              const float2* __restrict__ tab) {
  constexpr int K = 768;
  // [2 bufs][A 8KB | B 8KB]; reused by the epilogue transposes.
  __shared__ __align__(16) char SM[2][16384];
  const int tid = threadIdx.x;
  const int w = tid >> 6, lane = tid & 63;
  const int quad = lane >> 4, l15 = lane & 15;
  const int wrow = w >> 1, wcol = w & 1;
  const int m0 = blockIdx.x * 128, n0 = blockIdx.y * 128;

  f32x4 acc[4][4];
#pragma unroll
  for (int mt = 0; mt < 4; ++mt)
#pragma unroll
    for (int nt = 0; nt < 4; ++nt) acc[mt][nt] = (f32x4){0.f, 0.f, 0.f, 0.f};

  auto stage = [&](int k0, int bufi) {
#pragma unroll
    for (int i = 0; i < 2; ++i) {
      int L = i * 256 + tid;          // chunk index 0..511
      int r = L >> 2, cl = L & 3;
      int cg = cl ^ ((r >> 1) & 3);   // swizzle: conflict-free frag reads
      gl_lds16(A + (size_t)(m0 + r) * K + k0 + cg * 8, SM[bufi] + (i * 256 + w * 64) * 16);
      gl_lds16(Bm + (size_t)(n0 + r) * K + k0 + cg * 8, SM[bufi] + 8192 + (i * 256 + w * 64) * 16);
    }
  };

  stage(0, 0);
  int buf = 0;

  for (int k0 = 0; k0 < K; k0 += 32) {
    __syncthreads();                 // drains stage(k0) (issued last iter)
    if (k0 + 32 < K) stage(k0 + 32, buf ^ 1);
    const char* Ab = SM[buf];
    const char* Bb = SM[buf] + 8192;

    bf16x8 af[4], bfr[4];
#pragma unroll
    for (int mt = 0; mt < 4; ++mt) {
      int r = wrow * 64 + mt * 16 + l15;
      int cl = quad ^ ((r >> 1) & 3);
      af[mt] = *(const bf16x8*)(Ab + r * 64 + cl * 16);
    }
#pragma unroll
    for (int nt = 0; nt < 4; ++nt) {
      int r = wcol * 64 + nt * 16 + l15;
      int cl = quad ^ ((r >> 1) & 3);
      bfr[nt] = *(const bf16x8*)(Bb + r * 64 + cl * 16);
    }
#pragma unroll
    for (int mt = 0; mt < 4; ++mt)
#pragma unroll
      for (int nt = 0; nt < 4; ++nt)
        acc[mt][nt] = mfma32(af[mt], bfr[nt], acc[mt][nt]);
    buf ^= 1;
  }

  const int mat = n0 / 768;            // block-uniform (768 % 128 == 0)
  const int bb = m0 >> 11, s0 = m0 & 2047;
  const int hh0 = (n0 % 768) >> 6;     // first of the 2 heads this block covers
  if (mat == 2) {
    // ---- V: transpose via LDS, coalesced Vout[b][h][64][2048] stores ----
    constexpr int PITCH = 136;         // bf16; 16B-aligned rows, 2-way-free banks
    bf16* T = (bf16*)&SM[0][0];
#pragma unroll
    for (int hh = 0; hh < 2; ++hh) {
      __syncthreads();                 // LDS free (K-loop / previous head done)
      if (wcol == hh) {                // this wave's acc holds head hh
#pragma unroll
        for (int mt = 0; mt < 4; ++mt)
#pragma unroll
          for (int nt = 0; nt < 4; ++nt)
#pragma unroll
            for (int r = 0; r < 4; ++r) {
              int s_local = wrow * 64 + mt * 16 + quad * 4 + r; // 0..127
              int d_local = nt * 16 + l15;                      // 0..63
              T[d_local * PITCH + s_local] = (bf16)acc[mt][nt][r];
            }
      }
      __syncthreads();
      // read out rows, store coalesced: thread t -> row t>>2, 64B chunk t&3
      {
        int row = tid >> 2, chunk = tid & 3;
        const bf16* src = T + row * PITCH + chunk * 32;
        bf16x8 v0 = ((const bf16x8*)src)[0];
        bf16x8 v1 = ((const bf16x8*)src)[1];
        bf16x8 v2 = ((const bf16x8*)src)[2];
        bf16x8 v3 = ((const bf16x8*)src)[3];
        bf16* dst = Vout + (((size_t)(bb * 12 + hh0 + hh) * 64 + row) * 2048) + s0 + chunk * 32;
        ((bf16x8*)dst)[0] = v0;
        ((bf16x8*)dst)[1] = v1;
        ((bf16x8*)dst)[2] = v2;
        ((bf16x8*)dst)[3] = v3;
      }
    }
  } else {
    // ---- Q/K: RoPE in regs, then LDS transpose -> coalesced row stores ----
    // T: [128 s][PITCH=80 d] bf16 = 20.5KB. Write: 16 lanes span 8 banks
    // 2-way (free); quads at byte-stride 160 = 8-bank steps (disjoint).
    // Read: 64B/thread row-chunks, wave covers 4KB contiguous global.
    constexpr int PITCH = 80;
    bf16* T = (bf16*)&SM[0][0];
    const float sc = (mat == 0) ? 0.18033688011112042f : 1.0f; // 1/sqrt(64)*log2(e)
#pragma unroll
    for (int hh = 0; hh < 2; ++hh) {
      __syncthreads();                 // LDS free (K-loop / previous head done)
      if (wcol == hh) {                // this wave's acc holds head hh
#pragma unroll
        for (int mt = 0; mt < 4; ++mt)
#pragma unroll
          for (int nt = 0; nt < 4; ++nt)
#pragma unroll
            for (int r = 0; r < 4; ++r) {
              int s_local = wrow * 64 + mt * 16 + quad * 4 + r; // 0..127
              int d = nt * 16 + l15;                            // 0..63
              int m = m0 + s_local;
              float v = acc[mt][nt][r];
              // RoPE: pair partner lives in the adjacent lane (d^1).
              float partner = __shfl_xor(v, 1);
              float2 t = tab[((size_t)m << 5) + (d >> 1)];      // (cos, sin)
              float out = (v * t.x + ((d & 1) ? partner : -partner) * t.y) * sc;
              T[s_local * PITCH + d] = (bf16)out;
            }
      }
      __syncthreads();
      // read rows, store coalesced: thread t -> row t>>1, 64B chunk t&1
      {
        int row = tid >> 1, chunk = tid & 1;
        const bf16* src = T + row * PITCH + chunk * 32;
        bf16x8 v0 = ((const bf16x8*)src)[0];
        bf16x8 v1 = ((const bf16x8*)src)[1];
        bf16x8 v2 = ((const bf16x8*)src)[2];
        bf16x8 v3 = ((const bf16x8*)src)[3];
        bf16* dst = Cout + (((size_t)(mat * 4 + bb) * 12 + (hh0 + hh)) * 2048 + s0 + row) * 64 + chunk * 32;
        ((bf16x8*)dst)[0] = v0;
        ((bf16x8*)dst)[1] = v1;
        ((bf16x8*)dst)[2] = v2;
        ((bf16x8*)dst)[3] = v3;
      }
    }
  }
}

// ---------------- GEMM (output proj): C[M][N] = A[M][K]*B[N][K]^T, fp32 out
// 64x128 tile, flat grid 768 with XCD remap (neutral, kept).
__global__ __launch_bounds__(256, 4)
void gemm_o(const bf16* __restrict__ A, const bf16* __restrict__ Bm,
            float* __restrict__ Cout) {
  constexpr int K = 768;
  __shared__ __align__(16) char As[2][64 * 64];  // 64 rows x 32 bf16, swizzled
  __shared__ __align__(16) char Bs[2][128 * 64]; // 128 rows x 32 bf16, swizzled
  const int tid = threadIdx.x;
  const int w = tid >> 6, lane = tid & 63;
  const int quad = lane >> 4, l15 = lane & 15;
  const int wrow = w >> 1, wcol = w & 1;
  const int f = blockIdx.x;                 // 0..767
  const int xcd = f & 7, j = f >> 3;        // j 0..95 = 16 mtiles x 6 ncols
  const int m0 = (xcd * 16 + j / 6) * 64;
  const int n0 = (j % 6) * 128;

  f32x4 acc[2][4];
#pragma unroll
  for (int mt = 0; mt < 2; ++mt)
#pragma unroll
    for (int nt = 0; nt < 4; ++nt) acc[mt][nt] = (f32x4){0.f, 0.f, 0.f, 0.f};

  auto stage = [&](int k0, int bufi) {
    {
      int L = tid;                    // A: 256 chunks (64 rows x 4)
      int r = L >> 2, cl = L & 3;
      int cg = cl ^ ((r >> 1) & 3);
      gl_lds16(A + (size_t)(m0 + r) * K + k0 + cg * 8, As[bufi] + (w * 64) * 16 + lane * 16);
    }
#pragma unroll
    for (int i = 0; i < 2; ++i) {     // B: 512 chunks (128 rows x 4)
      int L = i * 256 + tid;
      int r = L >> 2, cl = L & 3;
      int cg = cl ^ ((r >> 1) & 3);
      gl_lds16(Bm + (size_t)(n0 + r) * K + k0 + cg * 8, Bs[bufi] + (i * 256 + w * 64) * 16);
    }
  };

  stage(0, 0);
  int buf = 0;

  for (int k0 = 0; k0 < K; k0 += 32) {
    __syncthreads();
    if (k0 + 32 < K) stage(k0 + 32, buf ^ 1);
    const char* Ab = As[buf];
    const char* Bb = Bs[buf];

    bf16x8 af[2], bfr[4];
#pragma unroll
    for (int mt = 0; mt < 2; ++mt) {
      int r = wrow * 32 + mt * 16 + l15;
      int cl = quad ^ ((r >> 1) & 3);
      af[mt] = *(const bf16x8*)(Ab + r * 64 + cl * 16);
    }
#pragma unroll
    for (int nt = 0; nt < 4; ++nt) {
      int r = wcol * 64 + nt * 16 + l15;
      int cl = quad ^ ((r >> 1) & 3);
      bfr[nt] = *(const bf16x8*)(Bb + r * 64 + cl * 16);
    }
#pragma unroll
    for (int mt = 0; mt < 2; ++mt)
#pragma unroll
      for (int nt = 0; nt < 4; ++nt)
        acc[mt][nt] = mfma32(af[mt], bfr[nt], acc[mt][nt]);
    buf ^= 1;
  }

#pragma unroll
  for (int mt = 0; mt < 2; ++mt)
#pragma unroll
    for (int nt = 0; nt < 4; ++nt)
#pragma unroll
      for (int r = 0; r < 4; ++r) {
        int m = m0 + wrow * 32 + mt * 16 + quad * 4 + r;
        int n = n0 + wcol * 64 + nt * 16 + l15;
        Cout[(size_t)m * 768 + n] = acc[mt][nt][r];
      }
}

// ---------------- Flash attention (causal), 64 q/block, 2 waves ----
// R0 compute structure (proven local optimum) + XCD remap (neutral, kept).
// No setprio (R9: cost ~4us — 2 lockstep waves/block = m190 regime).
__global__ __launch_bounds__(128, 3)
void attn(const bf16* __restrict__ qkv, const bf16* __restrict__ vt,
          bf16* __restrict__ aout) {
  const int bx = blockIdx.x;                // 0..1535
  const int xcd = bx & 7, jb = bx >> 3;     // jb 0..191 = 32 qtiles x 6 bh
  const int qt = 31 - (jb / 6);             // longest-first within each XCD
  const int bh = xcd * 6 + (jb % 6);        // XCD-owned (b,h) group
  const int b = bh / 12, h = bh % 12;
  const int tid = threadIdx.x, w = tid >> 6, lane = tid & 63;
  const int quad = lane >> 4, l15 = lane & 15;
  const bf16* Q  = qkv + (size_t)bh * (2048 * 64);
  const bf16* Kp = qkv + (size_t)(48 + bh) * (2048 * 64);
  const bf16* Vt = vt + (size_t)bh * (64 * 2048);
  __shared__ __align__(16) char Ks[2][64 * 128]; // 64 keys x 64 d, swizzled chunks
  __shared__ __align__(16) char Vs[2][64 * 128]; // 64 d x 64 keys, swizzled chunks

  const int qbase = qt * 64 + w * 32; // wave's 32 queries: [qbase, qbase+32)
  bf16x8 qf[2][2];
#pragma unroll
  for (int j = 0; j < 2; ++j) {
    qf[j][0] = *(const bf16x8*)(Q + (size_t)(qbase + j * 16 + l15) * 64 + quad * 8);
    qf[j][1] = *(const bf16x8*)(Q + (size_t)(qbase + j * 16 + l15) * 64 + 32 + quad * 8);
  }

  float li[2] = {0.f, 0.f};
  f32x4 o[2][4];
#pragma unroll
  for (int j = 0; j < 2; ++j)
#pragma unroll
    for (int dt = 0; dt < 4; ++dt) o[j][dt] = (f32x4){0.f, 0.f, 0.f, 0.f};

  // stage K/V tile kb into LDS buffer bufi (async; drained by next barrier)
  auto stage = [&](int kb, int bufi) {
#pragma unroll
    for (int i = 0; i < 4; ++i) {
      int L = i * 128 + tid;          // chunk 0..511; lds dest = base + lane*16
      int r = L >> 3, cl = L & 7, cg = cl ^ (r & 7);
      gl_lds16(Kp + (size_t)(kb * 64 + r) * 64 + cg * 8, Ks[bufi] + L * 16);
      gl_lds16(Vt + (size_t)r * 2048 + kb * 64 + cg * 8, Vs[bufi] + L * 16);
    }
  };

  stage(0, 0);
  int buf = 0;

  for (int kb = 0; kb <= qt; ++kb) {
    __syncthreads();               // drains vmcnt: tile kb resident, buf^1 free
    if (kb < qt) stage(kb + 1, buf ^ 1);
    const char* Kb = Ks[buf];
    const char* Vb = Vs[buf];

    // S^T tiles: lane holds S[query=qbase+j*16+l15][key=kb*64+sk*16+quad*4+rr]
    float S[2][16];
#pragma unroll
    for (int sk = 0; sk < 4; ++sk) {
      int r = sk * 16 + l15;
      int cl0 = quad ^ (r & 7);
      int cl1 = (4 + quad) ^ (r & 7);
      bf16x8 kf0 = *(const bf16x8*)(Kb + r * 128 + cl0 * 16);
      bf16x8 kf1 = *(const bf16x8*)(Kb + r * 128 + cl1 * 16);
#pragma unroll
      for (int j = 0; j < 2; ++j) {
        f32x4 st = (f32x4){0.f, 0.f, 0.f, 0.f};
        st = mfma32(kf0, qf[j][0], st);
        st = mfma32(kf1, qf[j][1], st);
#pragma unroll
        for (int rr = 0; rr < 4; ++rr) S[j][sk * 4 + rr] = st[rr]; // pre-scaled via Q
      }
    }
    if (kb == qt) { // diagonal tile: mask future keys
#pragma unroll
      for (int j = 0; j < 2; ++j)
#pragma unroll
        for (int sk = 0; sk < 4; ++sk)
#pragma unroll
          for (int rr = 0; rr < 4; ++rr) {
            int key = kb * 64 + sk * 16 + quad * 4 + rr;
            if (key > qbase + j * 16 + l15) S[j][sk * 4 + rr] = -1e30f;
          }
    }

#if HAVE_MFMA16
    s16x4 pf[2][4];
#endif
#pragma unroll
    for (int j = 0; j < 2; ++j) {
      float rs = 0.f;
#pragma unroll
      for (int sk = 0; sk < 4; ++sk) {
        bf16x4 pb;
#pragma unroll
        for (int rr = 0; rr < 4; ++rr) {
          float p = EXP2(S[j][sk * 4 + rr]);
          rs += p;
          pb[rr] = (bf16)p;
#if !HAVE_MFMA16
          S[j][sk * 4 + rr] = p;
#endif
        }
#if HAVE_MFMA16
        pf[j][sk] = __builtin_bit_cast(s16x4, pb);
#else
        (void)pb;
#endif
      }
      rs += __shfl_xor(rs, 16);
      rs += __shfl_xor(rs, 32);
      li[j] += rs;
    }

#if HAVE_MFMA16
    // P C/D layout == A-operand layout of 16x16x16: direct feed; V-frag
    // LDS reads shared across both q-subtiles.
#pragma unroll
    for (int sk = 0; sk < 4; ++sk)
#pragma unroll
      for (int dt = 0; dt < 4; ++dt) {
        int rr = dt * 16 + l15;                 // Vt row (d)
        int c = sk * 2 + (quad >> 1);           // 16B chunk along keys
        int cl = c ^ (rr & 7);
        s16x4 vf = *(const s16x4*)(Vb + rr * 128 + cl * 16 + (quad & 1) * 8);
        o[0][dt] = mfma16(pf[0][sk], vf, o[0][dt]);
        o[1][dt] = mfma16(pf[1][sk], vf, o[1][dt]);
      }
#else
    // Fallback: assemble A-frags for 16x16x32 PV via shuffles
#pragma unroll
    for (int j = 0; j < 2; ++j)
#pragma unroll
      for (int kc = 0; kc < 2; ++kc) {
        bf16x8 af;
#pragma unroll
        for (int jj = 0; jj < 8; ++jj) {
          int sq = (quad & 1) * 2 + (jj >> 2);
          int src = sq * 16 + l15;
          float v0 = __shfl(S[j][kc * 8 + (jj & 3)], src);
          float v1 = __shfl(S[j][kc * 8 + 4 + (jj & 3)], src);
          af[jj] = (bf16)((quad < 2) ? v0 : v1);
        }
#pragma unroll
        for (int dt = 0; dt < 4; ++dt) {
          int rr = dt * 16 + l15;
          int c = kc * 4 + quad;
          int cl = c ^ (rr & 7);
          bf16x8 vf = *(const bf16x8*)(Vb + rr * 128 + cl * 16);
          o[j][dt] = mfma32(af, vf, o[j][dt]);
        }
      }
#endif
    buf ^= 1;
  }

#pragma unroll
  for (int j = 0; j < 2; ++j) {
    float lr[4];
#pragma unroll
    for (int rr = 0; rr < 4; ++rr)
      lr[rr] = __builtin_amdgcn_rcpf(__shfl(li[j], quad * 4 + rr));
#pragma unroll
    for (int dt = 0; dt < 4; ++dt)
#pragma unroll
      for (int rr = 0; rr < 4; ++rr) {
        int q = qbase + j * 16 + quad * 4 + rr;
        int n = h * 64 + dt * 16 + l15;
        aout[((size_t)b * 2048 + q) * 768 + n] = (bf16)(o[j][dt][rr] * lr[rr]);
      }
  }
}

// ---------------- launch ----------------
extern "C" void kernel_launch(void* const* d_in, const int* in_sizes, int n_in,
                              void* d_out, int out_size, void* d_ws, size_t ws_size,
                              hipStream_t stream) {
  const float* x    = (const float*)d_in[0];
  const float* wqkv = (const float*)d_in[1];
  const float* wo   = (const float*)d_in[2];
  const int* tpos   = (const int*)d_in[3];
  const int* thetap = (const int*)d_in[5];

  char* ws = (char*)d_ws;
  // ws layout (bytes):
  bf16* xb    = (bf16*)(ws);              // 12,582,912  (reused as attn out)
  bf16* wqkvb = (bf16*)(ws + 12582912);   //  3,538,944
  bf16* wob   = (bf16*)(ws + 16121856);   //  1,179,648
  bf16* qkv   = (bf16*)(ws + 17301504);   // 37,748,736  [3][b][h][s][64] (mat==2 slot unused)
  bf16* vtb   = (bf16*)(ws + 55050240);   // 12,582,912  [b][h][64][2048]
  float2* tab = (float2*)(ws + 42467328); //  2,097,152  trig table, inside unused qkv mat==2 slot

  prep<<<9472, 256, 0, stream>>>(x, xb, wqkv, wqkvb, wo, wob, tpos, thetap, tab);
  gemm_qkv<<<dim3(64, 18), 256, 0, stream>>>(xb, wqkvb, qkv, vtb, tab);
  attn<<<1536, 128, 0, stream>>>(qkv, vtb, xb);
  gemm_o<<<768, 256, 0, stream>>>(xb, wob, (float*)d_out);
}

// Round 13
// 205.170 us; speedup vs baseline: 1.0160x; 1.0160x over previous
//
#include <hip/hip_runtime.h>
#include <hip/hip_bf16.h>

// Problem dims (hardcoded): B=4, S=2048, D=768, H=12, hd=64
//
// BEST CONFIG (R11 = 205.0us): attn(59.6) + gemm_qkv(~51) + gemm_o(~23)
// + prep(~10) + ~61us fixed. This round: revert R12's Q/K LDS-transpose
// epilogue (+3.4us — Q/K stores were already 32B-contiguous per 16-lane
// group; LDS round-trip only pays for fully-scattered stores like V's
// old 2B/line pattern). V-transpose epilogue kept (R9: -15us).
// Settled: attn R0 structure, no setprio (R9: -4us, lockstep regime);
// gemm_qkv 128x128 2-buffer; XCD remaps neutral-kept; R5 depth-2,
// R6 256-tile, R1/R4 attn restructures, R7 gemm ownership all negative.
typedef __bf16 bf16;
typedef __bf16 bf16x8 __attribute__((ext_vector_type(8)));
typedef __bf16 bf16x4 __attribute__((ext_vector_type(4)));
typedef short  s16x4  __attribute__((ext_vector_type(4)));
typedef float  f32x4  __attribute__((ext_vector_type(4)));

#if defined(__has_builtin)
#if __has_builtin(__builtin_amdgcn_mfma_f32_16x16x16bf16_1k)
#define HAVE_MFMA16 1
#endif
#if __has_builtin(__builtin_amdgcn_exp2f)
#define EXP2(x) __builtin_amdgcn_exp2f(x)
#else
#define EXP2(x) exp2f(x)
#endif
#else
#define EXP2(x) exp2f(x)
#endif

__device__ __forceinline__ void gl_lds16(const void* g, void* l) {
  __builtin_amdgcn_global_load_lds(
      (__attribute__((address_space(1))) const void*)g,
      (__attribute__((address_space(3))) void*)l, 16, 0, 0);
}

__device__ __forceinline__ f32x4 mfma32(bf16x8 a, bf16x8 b, f32x4 c) {
  return __builtin_amdgcn_mfma_f32_16x16x32_bf16(a, b, c, 0, 0, 0);
}
#if HAVE_MFMA16
__device__ __forceinline__ f32x4 mfma16(s16x4 a, s16x4 b, f32x4 c) {
  return __builtin_amdgcn_mfma_f32_16x16x16bf16_1k(a, b, c, 0, 0, 0);
}
#endif

// ---------------- prep: fp32->bf16 convert (x, W_QKV, W_O) + RoPE trig table
// tab[b*2048+s][d2] = (cos, sin) of pos*theta^(-d2/32).
__global__ void prep(const float* __restrict__ a, bf16* __restrict__ da,
                     const float* __restrict__ b, bf16* __restrict__ db,
                     const float* __restrict__ c, bf16* __restrict__ dc,
                     const int* __restrict__ tpos, const int* __restrict__ thetap,
                     float2* __restrict__ tab) {
  int bx = blockIdx.x;
  if (bx >= 8448) {                       // trig table blocks
    int i = (bx - 8448) * 256 + threadIdx.x; // < 4*2048*32 = 262144
    int d2 = i & 31;
    int bs = i >> 5;                      // b*2048+s
    float lt = log2f((float)(*thetap));
    float fr = exp2f(-(float)d2 * (1.0f / 32.0f) * lt); // theta^(-d2/32)
    float ang = (float)tpos[bs] * fr;
    float sn, cs;
    sincosf(ang, &sn, &cs);
    tab[i] = make_float2(cs, sn);
    return;
  }
  const float* s; bf16* d; int i;
  if (bx < 6144)      { s = a; d = da; i = bx * 256 + threadIdx.x; }
  else if (bx < 7872) { s = b; d = db; i = (bx - 6144) * 256 + threadIdx.x; }
  else                { s = c; d = dc; i = (bx - 7872) * 256 + threadIdx.x; }
  float4 v = ((const float4*)s)[i];
  bf16x4 o;
  o[0] = (bf16)v.x; o[1] = (bf16)v.y; o[2] = (bf16)v.z; o[3] = (bf16)v.w;
  ((bf16x4*)d)[i] = o;
}

// ---------------- GEMM (QKV): C = A[M][K] * B[N][K]^T, K=768, 128x128 tile
// 2-buffer skeleton, grid (64,18) default dispatch, launch_bounds(256,4).
// mat==2 (V) blocks transpose their tile through padded LDS and store
// Vout[b][h][64][2048] COALESCED (R9: -15us vs 2-byte scattered stores).
// Epilogue q,k: direct scatter to qkv[mat][b][h][s][64] WITH fused RoPE
// (pair partner via __shfl_xor(v,1)); Q scaled by 1/sqrt(64)*log2(e).
// (R12 tried LDS-transposing Q/K too: +3.4us — their stores are already
// 32B-contiguous per 16-lane group; do NOT route them through LDS.)
__global__ __launch_bounds__(256, 4)
void gemm_qkv(const bf16* __restrict__ A, const bf16* __restrict__ Bm,
              bf16* __restrict__ Cout, bf16* __restrict__ Vout,
              const float2* __restrict__ tab) {
  constexpr int K = 768;
  // [2 bufs][A 8KB | B 8KB]; also reused (17KB span) by the V-transpose.
  __shared__ __align__(16) char SM[2][16384];
  const int tid = threadIdx.x;
  const int w = tid >> 6, lane = tid & 63;
  const int quad = lane >> 4, l15 = lane & 15;
  const int wrow = w >> 1, wcol = w & 1;
  const int m0 = blockIdx.x * 128, n0 = blockIdx.y * 128;

  f32x4 acc[4][4];
#pragma unroll
  for (int mt = 0; mt < 4; ++mt)
#pragma unroll
    for (int nt = 0; nt < 4; ++nt) acc[mt][nt] = (f32x4){0.f, 0.f, 0.f, 0.f};

  auto stage = [&](int k0, int bufi) {
#pragma unroll
    for (int i = 0; i < 2; ++i) {
      int L = i * 256 + tid;          // chunk index 0..511
      int r = L >> 2, cl = L & 3;
      int cg = cl ^ ((r >> 1) & 3);   // swizzle: conflict-free frag reads
      gl_lds16(A + (size_t)(m0 + r) * K + k0 + cg * 8, SM[bufi] + (i * 256 + w * 64) * 16);
      gl_lds16(Bm + (size_t)(n0 + r) * K + k0 + cg * 8, SM[bufi] + 8192 + (i * 256 + w * 64) * 16);
    }
  };

  stage(0, 0);
  int buf = 0;

  for (int k0 = 0; k0 < K; k0 += 32) {
    __syncthreads();                 // drains stage(k0) (issued last iter)
    if (k0 + 32 < K) stage(k0 + 32, buf ^ 1);
    const char* Ab = SM[buf];
    const char* Bb = SM[buf] + 8192;

    bf16x8 af[4], bfr[4];
#pragma unroll
    for (int mt = 0; mt < 4; ++mt) {
      int r = wrow * 64 + mt * 16 + l15;
      int cl = quad ^ ((r >> 1) & 3);
      af[mt] = *(const bf16x8*)(Ab + r * 64 + cl * 16);
    }
#pragma unroll
    for (int nt = 0; nt < 4; ++nt) {
      int r = wcol * 64 + nt * 16 + l15;
      int cl = quad ^ ((r >> 1) & 3);
      bfr[nt] = *(const bf16x8*)(Bb + r * 64 + cl * 16);
    }
#pragma unroll
    for (int mt = 0; mt < 4; ++mt)
#pragma unroll
      for (int nt = 0; nt < 4; ++nt)
        acc[mt][nt] = mfma32(af[mt], bfr[nt], acc[mt][nt]);
    buf ^= 1;
  }

  const int mat = n0 / 768;            // block-uniform (768 % 128 == 0)
  if (mat == 2) {
    // ---- V: transpose via LDS, coalesced Vout[b][h][64][2048] stores ----
    constexpr int PITCH = 136;         // bf16; 16B-aligned rows, 2-way-free banks
    bf16* T = (bf16*)&SM[0][0];
    const int bb = m0 >> 11, s0 = m0 & 2047;
    const int hh0 = (n0 % 768) >> 6;   // first of the 2 heads this block covers
#pragma unroll
    for (int hh = 0; hh < 2; ++hh) {
      __syncthreads();                 // LDS free (K-loop / previous head done)
      if (wcol == hh) {                // this wave's acc holds head hh
#pragma unroll
        for (int mt = 0; mt < 4; ++mt)
#pragma unroll
          for (int nt = 0; nt < 4; ++nt)
#pragma unroll
            for (int r = 0; r < 4; ++r) {
              int s_local = wrow * 64 + mt * 16 + quad * 4 + r; // 0..127
              int d_local = nt * 16 + l15;                      // 0..63
              T[d_local * PITCH + s_local] = (bf16)acc[mt][nt][r];
            }
      }
      __syncthreads();
      // read out rows, store coalesced: thread t -> row t>>2, 64B chunk t&3
      {
        int row = tid >> 2, chunk = tid & 3;
        const bf16* src = T + row * PITCH + chunk * 32;
        bf16x8 v0 = ((const bf16x8*)src)[0];
        bf16x8 v1 = ((const bf16x8*)src)[1];
        bf16x8 v2 = ((const bf16x8*)src)[2];
        bf16x8 v3 = ((const bf16x8*)src)[3];
        bf16* dst = Vout + (((size_t)(bb * 12 + hh0 + hh) * 64 + row) * 2048) + s0 + chunk * 32;
        ((bf16x8*)dst)[0] = v0;
        ((bf16x8*)dst)[1] = v1;
        ((bf16x8*)dst)[2] = v2;
        ((bf16x8*)dst)[3] = v3;
      }
    }
  } else {
    // ---- Q/K: RoPE-fused direct scatter to qkv[mat][b][h][s][64] ----
#pragma unroll
    for (int mt = 0; mt < 4; ++mt)
#pragma unroll
      for (int nt = 0; nt < 4; ++nt)
#pragma unroll
        for (int r = 0; r < 4; ++r) {
          int m = m0 + wrow * 64 + mt * 16 + quad * 4 + r;
          int n = n0 + wcol * 64 + nt * 16 + l15;
          float v = acc[mt][nt][r];
          int rem = n % 768;
          int hh = rem >> 6, d = rem & 63;
          int bb = m >> 11, s = m & 2047;
          // RoPE: pair partner lives in the adjacent lane (d^1).
          float partner = __shfl_xor(v, 1);
          float2 t = tab[((size_t)m << 5) + ((rem >> 1) & 31)]; // (cos, sin)
          float out = v * t.x + ((n & 1) ? partner : -partner) * t.y;
          if (mat == 0) out *= 0.18033688011112042f; // 1/sqrt(64)*log2(e)
          Cout[(((size_t)(mat * 4 + bb) * 12 + hh) * 2048 + s) * 64 + d] = (bf16)out;
        }
  }
}

// ---------------- GEMM (output proj): C[M][N] = A[M][K]*B[N][K]^T, fp32 out
// 64x128 tile, flat grid 768 with XCD remap (neutral, kept).
__global__ __launch_bounds__(256, 4)
void gemm_o(const bf16* __restrict__ A, const bf16* __restrict__ Bm,
            float* __restrict__ Cout) {
  constexpr int K = 768;
  __shared__ __align__(16) char As[2][64 * 64];  // 64 rows x 32 bf16, swizzled
  __shared__ __align__(16) char Bs[2][128 * 64]; // 128 rows x 32 bf16, swizzled
  const int tid = threadIdx.x;
  const int w = tid >> 6, lane = tid & 63;
  const int quad = lane >> 4, l15 = lane & 15;
  const int wrow = w >> 1, wcol = w & 1;
  const int f = blockIdx.x;                 // 0..767
  const int xcd = f & 7, j = f >> 3;        // j 0..95 = 16 mtiles x 6 ncols
  const int m0 = (xcd * 16 + j / 6) * 64;
  const int n0 = (j % 6) * 128;

  f32x4 acc[2][4];
#pragma unroll
  for (int mt = 0; mt < 2; ++mt)
#pragma unroll
    for (int nt = 0; nt < 4; ++nt) acc[mt][nt] = (f32x4){0.f, 0.f, 0.f, 0.f};

  auto stage = [&](int k0, int bufi) {
    {
      int L = tid;                    // A: 256 chunks (64 rows x 4)
      int r = L >> 2, cl = L & 3;
      int cg = cl ^ ((r >> 1) & 3);
      gl_lds16(A + (size_t)(m0 + r) * K + k0 + cg * 8, As[bufi] + (w * 64) * 16 + lane * 16);
    }
#pragma unroll
    for (int i = 0; i < 2; ++i) {     // B: 512 chunks (128 rows x 4)
      int L = i * 256 + tid;
      int r = L >> 2, cl = L & 3;
      int cg = cl ^ ((r >> 1) & 3);
      gl_lds16(Bm + (size_t)(n0 + r) * K + k0 + cg * 8, Bs[bufi] + (i * 256 + w * 64) * 16);
    }
  };

  stage(0, 0);
  int buf = 0;

  for (int k0 = 0; k0 < K; k0 += 32) {
    __syncthreads();
    if (k0 + 32 < K) stage(k0 + 32, buf ^ 1);
    const char* Ab = As[buf];
    const char* Bb = Bs[buf];

    bf16x8 af[2], bfr[4];
#pragma unroll
    for (int mt = 0; mt < 2; ++mt) {
      int r = wrow * 32 + mt * 16 + l15;
      int cl = quad ^ ((r >> 1) & 3);
      af[mt] = *(const bf16x8*)(Ab + r * 64 + cl * 16);
    }
#pragma unroll
    for (int nt = 0; nt < 4; ++nt) {
      int r = wcol * 64 + nt * 16 + l15;
      int cl = quad ^ ((r >> 1) & 3);
      bfr[nt] = *(const bf16x8*)(Bb + r * 64 + cl * 16);
    }
#pragma unroll
    for (int mt = 0; mt < 2; ++mt)
#pragma unroll
      for (int nt = 0; nt < 4; ++nt)
        acc[mt][nt] = mfma32(af[mt], bfr[nt], acc[mt][nt]);
    buf ^= 1;
  }

#pragma unroll
  for (int mt = 0; mt < 2; ++mt)
#pragma unroll
    for (int nt = 0; nt < 4; ++nt)
#pragma unroll
      for (int r = 0; r < 4; ++r) {
        int m = m0 + wrow * 32 + mt * 16 + quad * 4 + r;
        int n = n0 + wcol * 64 + nt * 16 + l15;
        Cout[(size_t)m * 768 + n] = acc[mt][nt][r];
      }
}

// ---------------- Flash attention (causal), 64 q/block, 2 waves ----
// R0 compute structure (proven local optimum) + XCD remap (neutral, kept).
// No setprio (R9: cost ~4us — 2 lockstep waves/block = m190 regime).
__global__ __launch_bounds__(128, 3)
void attn(const bf16* __restrict__ qkv, const bf16* __restrict__ vt,
          bf16* __restrict__ aout) {
  const int bx = blockIdx.x;                // 0..1535
  const int xcd = bx & 7, jb = bx >> 3;     // jb 0..191 = 32 qtiles x 6 bh
  const int qt = 31 - (jb / 6);             // longest-first within each XCD
  const int bh = xcd * 6 + (jb % 6);        // XCD-owned (b,h) group
  const int b = bh / 12, h = bh % 12;
  const int tid = threadIdx.x, w = tid >> 6, lane = tid & 63;
  const int quad = lane >> 4, l15 = lane & 15;
  const bf16* Q  = qkv + (size_t)bh * (2048 * 64);
  const bf16* Kp = qkv + (size_t)(48 + bh) * (2048 * 64);
  const bf16* Vt = vt + (size_t)bh * (64 * 2048);
  __shared__ __align__(16) char Ks[2][64 * 128]; // 64 keys x 64 d, swizzled chunks
  __shared__ __align__(16) char Vs[2][64 * 128]; // 64 d x 64 keys, swizzled chunks

  const int qbase = qt * 64 + w * 32; // wave's 32 queries: [qbase, qbase+32)
  bf16x8 qf[2][2];
#pragma unroll
  for (int j = 0; j < 2; ++j) {
    qf[j][0] = *(const bf16x8*)(Q + (size_t)(qbase + j * 16 + l15) * 64 + quad * 8);
    qf[j][1] = *(const bf16x8*)(Q + (size_t)(qbase + j * 16 + l15) * 64 + 32 + quad * 8);
  }

  float li[2] = {0.f, 0.f};
  f32x4 o[2][4];
#pragma unroll
  for (int j = 0; j < 2; ++j)
#pragma unroll
    for (int dt = 0; dt < 4; ++dt) o[j][dt] = (f32x4){0.f, 0.f, 0.f, 0.f};

  // stage K/V tile kb into LDS buffer bufi (async; drained by next barrier)
  auto stage = [&](int kb, int bufi) {
#pragma unroll
    for (int i = 0; i < 4; ++i) {
      int L = i * 128 + tid;          // chunk 0..511; lds dest = base + lane*16
      int r = L >> 3, cl = L & 7, cg = cl ^ (r & 7);
      gl_lds16(Kp + (size_t)(kb * 64 + r) * 64 + cg * 8, Ks[bufi] + L * 16);
      gl_lds16(Vt + (size_t)r * 2048 + kb * 64 + cg * 8, Vs[bufi] + L * 16);
    }
  };

  stage(0, 0);
  int buf = 0;

  for (int kb = 0; kb <= qt; ++kb) {
    __syncthreads();               // drains vmcnt: tile kb resident, buf^1 free
    if (kb < qt) stage(kb + 1, buf ^ 1);
    const char* Kb = Ks[buf];
    const char* Vb = Vs[buf];

    // S^T tiles: lane holds S[query=qbase+j*16+l15][key=kb*64+sk*16+quad*4+rr]
    float S[2][16];
#pragma unroll
    for (int sk = 0; sk < 4; ++sk) {
      int r = sk * 16 + l15;
      int cl0 = quad ^ (r & 7);
      int cl1 = (4 + quad) ^ (r & 7);
      bf16x8 kf0 = *(const bf16x8*)(Kb + r * 128 + cl0 * 16);
      bf16x8 kf1 = *(const bf16x8*)(Kb + r * 128 + cl1 * 16);
#pragma unroll
      for (int j = 0; j < 2; ++j) {
        f32x4 st = (f32x4){0.f, 0.f, 0.f, 0.f};
        st = mfma32(kf0, qf[j][0], st);
        st = mfma32(kf1, qf[j][1], st);
#pragma unroll
        for (int rr = 0; rr < 4; ++rr) S[j][sk * 4 + rr] = st[rr]; // pre-scaled via Q
      }
    }
    if (kb == qt) { // diagonal tile: mask future keys
#pragma unroll
      for (int j = 0; j < 2; ++j)
#pragma unroll
        for (int sk = 0; sk < 4; ++sk)
#pragma unroll
          for (int rr = 0; rr < 4; ++rr) {
            int key = kb * 64 + sk * 16 + quad * 4 + rr;
            if (key > qbase + j * 16 + l15) S[j][sk * 4 + rr] = -1e30f;
          }
    }

#if HAVE_MFMA16
    s16x4 pf[2][4];
#endif
#pragma unroll
    for (int j = 0; j < 2; ++j) {
      float rs = 0.f;
#pragma unroll
      for (int sk = 0; sk < 4; ++sk) {
        bf16x4 pb;
#pragma unroll
        for (int rr = 0; rr < 4; ++rr) {
          float p = EXP2(S[j][sk * 4 + rr]);
          rs += p;
          pb[rr] = (bf16)p;
#if !HAVE_MFMA16
          S[j][sk * 4 + rr] = p;
#endif
        }
#if HAVE_MFMA16
        pf[j][sk] = __builtin_bit_cast(s16x4, pb);
#else
        (void)pb;
#endif
      }
      rs += __shfl_xor(rs, 16);
      rs += __shfl_xor(rs, 32);
      li[j] += rs;
    }

#if HAVE_MFMA16
    // P C/D layout == A-operand layout of 16x16x16: direct feed; V-frag
    // LDS reads shared across both q-subtiles.
#pragma unroll
    for (int sk = 0; sk < 4; ++sk)
#pragma unroll
      for (int dt = 0; dt < 4; ++dt) {
        int rr = dt * 16 + l15;                 // Vt row (d)
        int c = sk * 2 + (quad >> 1);           // 16B chunk along keys
        int cl = c ^ (rr & 7);
        s16x4 vf = *(const s16x4*)(Vb + rr * 128 + cl * 16 + (quad & 1) * 8);
        o[0][dt] = mfma16(pf[0][sk], vf, o[0][dt]);
        o[1][dt] = mfma16(pf[1][sk], vf, o[1][dt]);
      }
#else
    // Fallback: assemble A-frags for 16x16x32 PV via shuffles
#pragma unroll
    for (int j = 0; j < 2; ++j)
#pragma unroll
      for (int kc = 0; kc < 2; ++kc) {
        bf16x8 af;
#pragma unroll
        for (int jj = 0; jj < 8; ++jj) {
          int sq = (quad & 1) * 2 + (jj >> 2);
          int src = sq * 16 + l15;
          float v0 = __shfl(S[j][kc * 8 + (jj & 3)], src);
          float v1 = __shfl(S[j][kc * 8 + 4 + (jj & 3)], src);
          af[jj] = (bf16)((quad < 2) ? v0 : v1);
        }
#pragma unroll
        for (int dt = 0; dt < 4; ++dt) {
          int rr = dt * 16 + l15;
          int c = kc * 4 + quad;
          int cl = c ^ (rr & 7);
          bf16x8 vf = *(const bf16x8*)(Vb + rr * 128 + cl * 16);
          o[j][dt] = mfma32(af, vf, o[j][dt]);
        }
      }
#endif
    buf ^= 1;
  }

#pragma unroll
  for (int j = 0; j < 2; ++j) {
    float lr[4];
#pragma unroll
    for (int rr = 0; rr < 4; ++rr)
      lr[rr] = __builtin_amdgcn_rcpf(__shfl(li[j], quad * 4 + rr));
#pragma unroll
    for (int dt = 0; dt < 4; ++dt)
#pragma unroll
      for (int rr = 0; rr < 4; ++rr) {
        int q = qbase + j * 16 + quad * 4 + rr;
        int n = h * 64 + dt * 16 + l15;
        aout[((size_t)b * 2048 + q) * 768 + n] = (bf16)(o[j][dt][rr] * lr[rr]);
      }
  }
}

// ---------------- launch ----------------
extern "C" void kernel_launch(void* const* d_in, const int* in_sizes, int n_in,
                              void* d_out, int out_size, void* d_ws, size_t ws_size,
                              hipStream_t stream) {
  const float* x    = (const float*)d_in[0];
  const float* wqkv = (const float*)d_in[1];
  const float* wo   = (const float*)d_in[2];
  const int* tpos   = (const int*)d_in[3];
  const int* thetap = (const int*)d_in[5];

  char* ws = (char*)d_ws;
  // ws layout (bytes):
  bf16* xb    = (bf16*)(ws);              // 12,582,912  (reused as attn out)
  bf16* wqkvb = (bf16*)(ws + 12582912);   //  3,538,944
  bf16* wob   = (bf16*)(ws + 16121856);   //  1,179,648
  bf16* qkv   = (bf16*)(ws + 17301504);   // 37,748,736  [3][b][h][s][64] (mat==2 slot unused)
  bf16* vtb   = (bf16*)(ws + 55050240);   // 12,582,912  [b][h][64][2048]
  float2* tab = (float2*)(ws + 42467328); //  2,097,152  trig table, inside unused qkv mat==2 slot

  prep<<<9472, 256, 0, stream>>>(x, xb, wqkv, wqkvb, wo, wob, tpos, thetap, tab);
  gemm_qkv<<<dim3(64, 18), 256, 0, stream>>>(xb, wqkvb, qkv, vtb, tab);
  attn<<<1536, 128, 0, stream>>>(qkv, vtb, xb);
  gemm_o<<<768, 256, 0, stream>>>(xb, wob, (float*)d_out);
}